// Round 8
// baseline (124.472 us; speedup 1.0000x reference)
//
#include <hip/hip_runtime.h>

#define D 128
#define TILE_N 64
#define HPITCH 132   // bf16 pitch for epilogue LDS tile -> conflict-free banks

typedef __attribute__((ext_vector_type(8))) short  short8;
typedef __attribute__((ext_vector_type(4))) float  f32x4;

__device__ inline unsigned short f32_to_bf16(float f) {
    unsigned int u = __float_as_uint(f);
    unsigned int r = (u + 0x7FFFu + ((u >> 16) & 1u)) >> 16;   // RNE
    return (unsigned short)r;
}
__device__ inline float bf16_to_f32(unsigned short s) {
    return __uint_as_float(((unsigned int)s) << 16);
}
__device__ inline short8 pack_bf16x8(float4 a, float4 b) {
    short8 u;
    u[0] = (short)f32_to_bf16(a.x); u[1] = (short)f32_to_bf16(a.y);
    u[2] = (short)f32_to_bf16(a.z); u[3] = (short)f32_to_bf16(a.w);
    u[4] = (short)f32_to_bf16(b.x); u[5] = (short)f32_to_bf16(b.y);
    u[6] = (short)f32_to_bf16(b.z); u[7] = (short)f32_to_bf16(b.w);
    return u;
}

// ---- zero: custom buffer zeroing (rocclr fill is latency-horrible) ---------
__global__ __launch_bounds__(256) void zero_kernel(int* __restrict__ p, int n)
{
    int i = blockIdx.x * 256 + threadIdx.x;
    if (i < n) p[i] = 0;
}

// ---- prep: W (f32) -> Wb (bf16) once; fused dst-histogram ------------------
__global__ __launch_bounds__(256) void prep_kernel(
    const float* __restrict__ W, unsigned short* __restrict__ Wb,
    const int* __restrict__ dst, int* __restrict__ cnt, int n_edges)
{
    const int tid = blockIdx.x * 256 + threadIdx.x;
    if (tid < (D * D) / 8) {
        float4 v0 = *(const float4*)&W[tid * 8];
        float4 v1 = *(const float4*)&W[tid * 8 + 4];
        *(short8*)&Wb[tid * 8] = pack_bf16x8(v0, v1);
    }
    const int stride = gridDim.x * 256;
    for (int i = tid; i < n_edges; i += stride)
        atomicAdd(&cnt[dst[i]], 1);
}

// ---- GEMM: h(bf16) = relu(x @ W^T + b) * (mask_u >= 0.5) * 2 ---------------
__global__ __launch_bounds__(256, 4) void gemm_mfma_kernel(
    const float* __restrict__ x, const unsigned short* __restrict__ Wb,
    const float* __restrict__ bias, const float* __restrict__ mask_u,
    unsigned short* __restrict__ h, int n_nodes)
{
    __shared__ unsigned short ht[TILE_N * HPITCH];   // 16896 B
    const int t    = threadIdx.x;
    const int lane = t & 63;
    const int w    = t >> 6;
    const int fr   = lane & 15;
    const int fg   = lane >> 4;

    const int n0 = blockIdx.x * TILE_N;

    float bs[8];
    #pragma unroll
    for (int c = 0; c < 8; ++c) bs[c] = bias[16 * c + fr];

    int arow = n0 + 16 * w + fr;
    if (arow >= n_nodes) arow = n_nodes - 1;
    const float* xrow = x + (size_t)arow * D;

    f32x4 acc[8];
    #pragma unroll
    for (int c = 0; c < 8; ++c) acc[c] = (f32x4){0.f, 0.f, 0.f, 0.f};

    #pragma unroll
    for (int s = 0; s < 4; ++s) {
        float4 a0 = *(const float4*)&xrow[s * 32 + fg * 8];
        float4 a1 = *(const float4*)&xrow[s * 32 + fg * 8 + 4];
        short8 a  = pack_bf16x8(a0, a1);
        #pragma unroll
        for (int c = 0; c < 8; ++c) {
            short8 b = *(const short8*)&Wb[(16 * c + fr) * D + s * 32 + fg * 8];
            acc[c] = __builtin_amdgcn_mfma_f32_16x16x32_bf16(a, b, acc[c], 0, 0, 0);
        }
    }

    #pragma unroll
    for (int c = 0; c < 8; ++c) {
        const int col = 16 * c + fr;
        #pragma unroll
        for (int r = 0; r < 4; ++r) {
            const int rl = 16 * w + fg * 4 + r;
            float v = fmaxf(acc[c][r] + bs[c], 0.f);
            ht[rl * HPITCH + col] = f32_to_bf16(v);
        }
    }
    __syncthreads();

    const int cg = t & 15;
    const int r0 = t >> 4;
    #pragma unroll
    for (int rr = 0; rr < 4; ++rr) {
        const int row  = 16 * rr + r0;
        const int node = n0 + row;
        if (node < n_nodes) {
            short8 hv = *(const short8*)&ht[row * HPITCH + cg * 8];
            const size_t off = (size_t)node * D + cg * 8;
            float4 m0 = *(const float4*)&mask_u[off];
            float4 m1 = *(const float4*)&mask_u[off + 4];
            short8 o;
            #pragma unroll
            for (int j = 0; j < 8; ++j) {
                float mk = (j < 4) ? ((const float*)&m0)[j] : ((const float*)&m1)[j - 4];
                float v  = bf16_to_f32((unsigned short)hv[j]) * 2.f;
                o[j] = (mk >= 0.5f) ? (short)f32_to_bf16(v) : (short)0;
            }
            *(short8*)&h[off] = o;
        }
    }
}

// ---------------- CSR build: scan + bucket scatter --------------------------
__global__ __launch_bounds__(256) void scan_partial_kernel(
    const int* __restrict__ cnt, int* __restrict__ bsum, int n)
{
    __shared__ int s[256];
    int t = threadIdx.x;
    int i = blockIdx.x * 256 + t;
    s[t] = (i < n) ? cnt[i] : 0;
    __syncthreads();
    for (int o = 128; o > 0; o >>= 1) {
        if (t < o) s[t] += s[t + o];
        __syncthreads();
    }
    if (t == 0) bsum[blockIdx.x] = s[0];
}

__global__ __launch_bounds__(256) void scan_bsum_kernel(int* __restrict__ bsum, int nb)
{
    __shared__ int s[256];
    int t = threadIdx.x;
    int v = (t < nb) ? bsum[t] : 0;
    s[t] = v;
    __syncthreads();
    for (int o = 1; o < 256; o <<= 1) {
        int add = (t >= o) ? s[t - o] : 0;
        __syncthreads();
        s[t] += add;
        __syncthreads();
    }
    if (t < nb) bsum[t] = s[t] - v;   // exclusive
}

__global__ __launch_bounds__(256) void scan_final_kernel(
    int* __restrict__ offs, const int* __restrict__ bsum, int n)
{
    __shared__ int s[256];
    int t = threadIdx.x;
    int i = blockIdx.x * 256 + t;
    int v = (i < n) ? offs[i] : 0;
    s[t] = v;
    __syncthreads();
    for (int o = 1; o < 256; o <<= 1) {
        int add = (t >= o) ? s[t - o] : 0;
        __syncthreads();
        s[t] += add;
        __syncthreads();
    }
    if (i < n) offs[i] = s[t] - v + bsum[blockIdx.x];
}

__global__ __launch_bounds__(256) void scatter_build_kernel(
    const int* __restrict__ src, const int* __restrict__ dst,
    int* __restrict__ offs, int* __restrict__ srcs, int n_edges)
{
    int i = blockIdx.x * 256 + threadIdx.x;
    if (i < n_edges) {
        int pos = atomicAdd(&offs[dst[i]], 1);
        srcs[pos] = src[i];
    }
}

// ---- Gather-reduce (bf16 h): one WAVE per node -----------------------------
// 64 lanes = 4 edge-slots x 16 col-lanes. Each slot strides edges by 4,
// 2-deep unroll (8 loads in flight/wave). Cross-slot shfl_xor reduce at end.
__global__ __launch_bounds__(256) void gather_reduce_kernel(
    const unsigned short* __restrict__ h, const int* __restrict__ srcs,
    const int* __restrict__ offs, float* __restrict__ out, int n_nodes)
{
    const int t    = threadIdx.x;
    const int lane = t & 63;
    const int node = blockIdx.x * 4 + (t >> 6);
    if (node >= n_nodes) return;
    const int eg = lane >> 4;          // edge slot 0..3
    const int cb = (lane & 15) * 8;    // 8 bf16 cols
    const int start = (node == 0) ? 0 : offs[node - 1];
    const int end   = offs[node];

    float acc[8];
    #pragma unroll
    for (int j = 0; j < 8; ++j) acc[j] = 0.f;

    int i = start + eg;
    for (; i + 4 < end; i += 8) {      // both i and i+4 valid
        int s0 = srcs[i];
        int s1 = srcs[i + 4];
        short8 v0 = *(const short8*)&h[(size_t)s0 * D + cb];
        short8 v1 = *(const short8*)&h[(size_t)s1 * D + cb];
        #pragma unroll
        for (int j = 0; j < 8; ++j)
            acc[j] += bf16_to_f32((unsigned short)v0[j]) +
                      bf16_to_f32((unsigned short)v1[j]);
    }
    if (i < end) {
        int s0 = srcs[i];
        short8 v0 = *(const short8*)&h[(size_t)s0 * D + cb];
        #pragma unroll
        for (int j = 0; j < 8; ++j) acc[j] += bf16_to_f32((unsigned short)v0[j]);
    }

    // reduce across the 4 edge slots (lanes differing in bits 4,5)
    #pragma unroll
    for (int j = 0; j < 8; ++j) {
        acc[j] += __shfl_xor(acc[j], 16, 64);
        acc[j] += __shfl_xor(acc[j], 32, 64);
    }

    if (eg == 0) {
        f32x4 o0 = (f32x4){acc[0], acc[1], acc[2], acc[3]};
        f32x4 o1 = (f32x4){acc[4], acc[5], acc[6], acc[7]};
        __builtin_nontemporal_store(o0, (f32x4*)&out[(size_t)node * D + cb]);
        __builtin_nontemporal_store(o1, (f32x4*)&out[(size_t)node * D + cb + 4]);
    }
}

// ---------------- Fallback: direct atomic scatter (bf16 h) ------------------
__global__ __launch_bounds__(256) void scatter_atomic_kernel(
    const unsigned short* __restrict__ h, const int* __restrict__ src,
    const int* __restrict__ dst, float* __restrict__ out, int n_edges)
{
    const int t = threadIdx.x;
    const int e = blockIdx.x * 16 + (t >> 4);
    if (e >= n_edges) return;
    const int cb = (t & 15) * 8;
    const int s  = src[e];
    const int dd = dst[e];
    short8 v = *(const short8*)&h[(size_t)s * D + cb];
    float* o = &out[(size_t)dd * D + cb];
    #pragma unroll
    for (int j = 0; j < 8; ++j) atomicAdd(o + j, bf16_to_f32((unsigned short)v[j]));
}

extern "C" void kernel_launch(void* const* d_in, const int* in_sizes, int n_in,
                              void* d_out, int out_size, void* d_ws, size_t ws_size,
                              hipStream_t stream) {
    const float* x      = (const float*)d_in[0];
    const float* W      = (const float*)d_in[1];
    const float* bias   = (const float*)d_in[2];
    const float* mask_u = (const float*)d_in[3];
    const int*   src    = (const int*)d_in[4];
    const int*   dst    = (const int*)d_in[5];
    float* out = (float*)d_out;

    const int n_nodes = in_sizes[0] / D;
    const int n_edges = in_sizes[4];
    const int n_tiles = (n_nodes + TILE_N - 1) / TILE_N;

    // ws layout: [Wb bf16 64KB][h bf16][offs][bsum 256][srcs]
    unsigned short* Wb = (unsigned short*)d_ws;
    const size_t wb_bytes = (size_t)D * D * sizeof(unsigned short);
    unsigned short* h  = (unsigned short*)((char*)d_ws + wb_bytes);
    const size_t h_bytes = (size_t)n_nodes * D * sizeof(unsigned short);
    int* offs = (int*)((char*)d_ws + wb_bytes + h_bytes);
    int* bsum = offs + n_nodes;
    int* srcs = bsum + 256;
    const size_t needed = wb_bytes + h_bytes +
                          ((size_t)n_nodes + 256 + n_edges) * sizeof(int);

    const int eb  = (n_edges + 255) / 256;
    const int nbk = (n_nodes + 255) / 256;
    const int pb  = (eb > 8) ? eb : 8;

    if (ws_size >= needed && nbk <= 256) {
        zero_kernel<<<nbk, 256, 0, stream>>>(offs, n_nodes);
        prep_kernel<<<pb, 256, 0, stream>>>(W, Wb, dst, offs, n_edges);
        gemm_mfma_kernel<<<n_tiles, 256, 0, stream>>>(
            x, Wb, bias, mask_u, h, n_nodes);
        scan_partial_kernel<<<nbk, 256, 0, stream>>>(offs, bsum, n_nodes);
        scan_bsum_kernel<<<1, 256, 0, stream>>>(bsum, nbk);
        scan_final_kernel<<<nbk, 256, 0, stream>>>(offs, bsum, n_nodes);
        scatter_build_kernel<<<eb, 256, 0, stream>>>(src, dst, offs, srcs, n_edges);
        gather_reduce_kernel<<<(n_nodes + 3) / 4, 256, 0, stream>>>(
            h, srcs, offs, out, n_nodes);
    } else {
        prep_kernel<<<8, 256, 0, stream>>>(W, Wb, dst, nullptr, 0);
        gemm_mfma_kernel<<<n_tiles, 256, 0, stream>>>(
            x, Wb, bias, mask_u, h, n_nodes);
        zero_kernel<<<(out_size + 255) / 256, 256, 0, stream>>>((int*)d_out, out_size);
        scatter_atomic_kernel<<<(n_edges + 15) / 16, 256, 0, stream>>>(
            h, src, dst, out, n_edges);
    }
}

// Round 9
// 100.091 us; speedup vs baseline: 1.2436x; 1.2436x over previous
//
#include <hip/hip_runtime.h>

#define D 128
#define TILE_N 64
#define HPITCH 132     // bf16 pitch for epilogue LDS tile -> conflict-free banks
#define CAP 48         // bucket capacity per node; Poisson(12), P(deg>48) ~ 1e-14
#define SPILL_MAX 8192

typedef __attribute__((ext_vector_type(8))) short  short8;
typedef __attribute__((ext_vector_type(4))) float  f32x4;

__device__ inline unsigned short f32_to_bf16(float f) {
    unsigned int u = __float_as_uint(f);
    unsigned int r = (u + 0x7FFFu + ((u >> 16) & 1u)) >> 16;   // RNE
    return (unsigned short)r;
}
__device__ inline float bf16_to_f32(unsigned short s) {
    return __uint_as_float(((unsigned int)s) << 16);
}
__device__ inline short8 pack_bf16x8(float4 a, float4 b) {
    short8 u;
    u[0] = (short)f32_to_bf16(a.x); u[1] = (short)f32_to_bf16(a.y);
    u[2] = (short)f32_to_bf16(a.z); u[3] = (short)f32_to_bf16(a.w);
    u[4] = (short)f32_to_bf16(b.x); u[5] = (short)f32_to_bf16(b.y);
    u[6] = (short)f32_to_bf16(b.z); u[7] = (short)f32_to_bf16(b.w);
    return u;
}

// ---- prep: W (f32) -> Wb (bf16); zero cnt + spill counter ------------------
__global__ __launch_bounds__(256) void prep_kernel(
    const float* __restrict__ W, unsigned short* __restrict__ Wb,
    int* __restrict__ cnt, int n_nodes, int* __restrict__ spill_cnt)
{
    const int tid = blockIdx.x * 256 + threadIdx.x;
    if (tid < (D * D) / 8) {
        float4 v0 = *(const float4*)&W[tid * 8];
        float4 v1 = *(const float4*)&W[tid * 8 + 4];
        *(short8*)&Wb[tid * 8] = pack_bf16x8(v0, v1);
    }
    if (cnt && tid < n_nodes) cnt[tid] = 0;
    if (spill_cnt && tid == 0) *spill_cnt = 0;
}

// ---- GEMM + fused edge bucket-scatter --------------------------------------
// h(bf16) = relu(x @ W^T + b) * (mask_u >= 0.5) * 2 ; then grid-stride edges:
// pos = atomicAdd(cnt[dst]); bucket[dst*CAP+pos] = src (spill on overflow).
__global__ __launch_bounds__(256, 4) void gemm_mfma_kernel(
    const float* __restrict__ x, const unsigned short* __restrict__ Wb,
    const float* __restrict__ bias, const float* __restrict__ mask_u,
    unsigned short* __restrict__ h, int n_nodes,
    const int* __restrict__ src, const int* __restrict__ dst, int n_edges,
    int* __restrict__ cnt, int* __restrict__ bucket,
    int* __restrict__ spill_cnt, int* __restrict__ spill)
{
    __shared__ unsigned short ht[TILE_N * HPITCH];   // 16896 B
    const int t    = threadIdx.x;
    const int lane = t & 63;
    const int w    = t >> 6;
    const int fr   = lane & 15;
    const int fg   = lane >> 4;

    const int n0 = blockIdx.x * TILE_N;

    float bs[8];
    #pragma unroll
    for (int c = 0; c < 8; ++c) bs[c] = bias[16 * c + fr];

    int arow = n0 + 16 * w + fr;
    if (arow >= n_nodes) arow = n_nodes - 1;
    const float* xrow = x + (size_t)arow * D;

    f32x4 acc[8];
    #pragma unroll
    for (int c = 0; c < 8; ++c) acc[c] = (f32x4){0.f, 0.f, 0.f, 0.f};

    #pragma unroll
    for (int s = 0; s < 4; ++s) {
        float4 a0 = *(const float4*)&xrow[s * 32 + fg * 8];
        float4 a1 = *(const float4*)&xrow[s * 32 + fg * 8 + 4];
        short8 a  = pack_bf16x8(a0, a1);
        #pragma unroll
        for (int c = 0; c < 8; ++c) {
            short8 b = *(const short8*)&Wb[(16 * c + fr) * D + s * 32 + fg * 8];
            acc[c] = __builtin_amdgcn_mfma_f32_16x16x32_bf16(a, b, acc[c], 0, 0, 0);
        }
    }

    #pragma unroll
    for (int c = 0; c < 8; ++c) {
        const int col = 16 * c + fr;
        #pragma unroll
        for (int r = 0; r < 4; ++r) {
            const int rl = 16 * w + fg * 4 + r;
            float v = fmaxf(acc[c][r] + bs[c], 0.f);
            ht[rl * HPITCH + col] = f32_to_bf16(v);
        }
    }
    __syncthreads();

    const int cg = t & 15;
    const int r0 = t >> 4;
    #pragma unroll
    for (int rr = 0; rr < 4; ++rr) {
        const int row  = 16 * rr + r0;
        const int node = n0 + row;
        if (node < n_nodes) {
            short8 hv = *(const short8*)&ht[row * HPITCH + cg * 8];
            const size_t off = (size_t)node * D + cg * 8;
            float4 m0 = *(const float4*)&mask_u[off];
            float4 m1 = *(const float4*)&mask_u[off + 4];
            short8 o;
            #pragma unroll
            for (int j = 0; j < 8; ++j) {
                float mk = (j < 4) ? ((const float*)&m0)[j] : ((const float*)&m1)[j - 4];
                float v  = bf16_to_f32((unsigned short)hv[j]) * 2.f;
                o[j] = (mk >= 0.5f) ? (short)f32_to_bf16(v) : (short)0;
            }
            *(short8*)&h[off] = o;
        }
    }

    // fused bucket-scatter tail (overlaps other blocks' tile work)
    const int stride = gridDim.x * 256;
    for (int i = blockIdx.x * 256 + t; i < n_edges; i += stride) {
        int dd  = dst[i];
        int ss  = src[i];
        int pos = atomicAdd(&cnt[dd], 1);
        if (pos < CAP) {
            bucket[dd * CAP + pos] = ss;
        } else {
            int k = atomicAdd(spill_cnt, 1);
            if (k < SPILL_MAX) { spill[2 * k] = dd; spill[2 * k + 1] = ss; }
        }
    }
}

// ---- Gather-reduce (bf16 h): 16 lanes/node over fixed-cap buckets ----------
__global__ __launch_bounds__(256) void gather_reduce_kernel(
    const unsigned short* __restrict__ h, const int* __restrict__ cnt,
    const int* __restrict__ bucket, float* __restrict__ out, int n_nodes)
{
    const int t = threadIdx.x;
    const int node = blockIdx.x * 16 + (t >> 4);
    if (node >= n_nodes) return;
    const int cb = (t & 15) * 8;
    int deg = cnt[node];
    if (deg > CAP) deg = CAP;
    const int* b = bucket + (size_t)node * CAP;

    float acc[8];
    #pragma unroll
    for (int j = 0; j < 8; ++j) acc[j] = 0.f;

    int i = 0;
    for (; i + 3 < deg; i += 4) {
        int s0 = b[i], s1 = b[i + 1], s2 = b[i + 2], s3 = b[i + 3];
        short8 v0 = *(const short8*)&h[(size_t)s0 * D + cb];
        short8 v1 = *(const short8*)&h[(size_t)s1 * D + cb];
        short8 v2 = *(const short8*)&h[(size_t)s2 * D + cb];
        short8 v3 = *(const short8*)&h[(size_t)s3 * D + cb];
        #pragma unroll
        for (int j = 0; j < 8; ++j)
            acc[j] += (bf16_to_f32((unsigned short)v0[j]) +
                       bf16_to_f32((unsigned short)v1[j])) +
                      (bf16_to_f32((unsigned short)v2[j]) +
                       bf16_to_f32((unsigned short)v3[j]));
    }
    for (; i < deg; ++i) {
        int s0 = b[i];
        short8 v0 = *(const short8*)&h[(size_t)s0 * D + cb];
        #pragma unroll
        for (int j = 0; j < 8; ++j) acc[j] += bf16_to_f32((unsigned short)v0[j]);
    }

    f32x4 o0 = (f32x4){acc[0], acc[1], acc[2], acc[3]};
    f32x4 o1 = (f32x4){acc[4], acc[5], acc[6], acc[7]};
    __builtin_nontemporal_store(o0, (f32x4*)&out[(size_t)node * D + cb]);
    __builtin_nontemporal_store(o1, (f32x4*)&out[(size_t)node * D + cb + 4]);
}

// ---- spill fix: apply overflow edges atomically (virtually never runs) -----
__global__ __launch_bounds__(256) void spill_apply_kernel(
    const unsigned short* __restrict__ h, const int* __restrict__ spill_cnt,
    const int* __restrict__ spill, float* __restrict__ out)
{
    int n = *spill_cnt;
    if (n > SPILL_MAX) n = SPILL_MAX;
    for (int e = threadIdx.x; e < n; e += 256) {
        int dd = spill[2 * e], ss = spill[2 * e + 1];
        for (int j = 0; j < D; ++j)
            atomicAdd(&out[(size_t)dd * D + j],
                      bf16_to_f32(h[(size_t)ss * D + j]));
    }
}

// ---- zero + fallback atomic scatter ----------------------------------------
__global__ __launch_bounds__(256) void zero_kernel(int* __restrict__ p, int n)
{
    int i = blockIdx.x * 256 + threadIdx.x;
    if (i < n) p[i] = 0;
}

__global__ __launch_bounds__(256) void scatter_atomic_kernel(
    const unsigned short* __restrict__ h, const int* __restrict__ src,
    const int* __restrict__ dst, float* __restrict__ out, int n_edges)
{
    const int t = threadIdx.x;
    const int e = blockIdx.x * 16 + (t >> 4);
    if (e >= n_edges) return;
    const int cb = (t & 15) * 8;
    const int s  = src[e];
    const int dd = dst[e];
    short8 v = *(const short8*)&h[(size_t)s * D + cb];
    float* o = &out[(size_t)dd * D + cb];
    #pragma unroll
    for (int j = 0; j < 8; ++j) atomicAdd(o + j, bf16_to_f32((unsigned short)v[j]));
}

extern "C" void kernel_launch(void* const* d_in, const int* in_sizes, int n_in,
                              void* d_out, int out_size, void* d_ws, size_t ws_size,
                              hipStream_t stream) {
    const float* x      = (const float*)d_in[0];
    const float* W      = (const float*)d_in[1];
    const float* bias   = (const float*)d_in[2];
    const float* mask_u = (const float*)d_in[3];
    const int*   src    = (const int*)d_in[4];
    const int*   dst    = (const int*)d_in[5];
    float* out = (float*)d_out;

    const int n_nodes = in_sizes[0] / D;
    const int n_edges = in_sizes[4];
    const int n_tiles = (n_nodes + TILE_N - 1) / TILE_N;

    // ws layout: [Wb 32KB][h bf16][cnt n][spill_cnt 1][spill 2*SPILL_MAX][bucket n*CAP]
    unsigned short* Wb = (unsigned short*)d_ws;
    const size_t wb_bytes = (size_t)D * D * sizeof(unsigned short);
    unsigned short* h  = (unsigned short*)((char*)d_ws + wb_bytes);
    const size_t h_bytes = (size_t)n_nodes * D * sizeof(unsigned short);
    int* cnt       = (int*)((char*)d_ws + wb_bytes + h_bytes);
    int* spill_cnt = cnt + n_nodes;
    int* spill     = spill_cnt + 1;
    int* bucket    = spill + 2 * SPILL_MAX;
    const size_t needed = wb_bytes + h_bytes +
        ((size_t)n_nodes + 1 + 2 * SPILL_MAX + (size_t)n_nodes * CAP) * sizeof(int);

    const int pbk = ((n_nodes > 2048 ? n_nodes : 2048) + 255) / 256;

    if (ws_size >= needed) {
        prep_kernel<<<pbk, 256, 0, stream>>>(W, Wb, cnt, n_nodes, spill_cnt);
        gemm_mfma_kernel<<<n_tiles, 256, 0, stream>>>(
            x, Wb, bias, mask_u, h, n_nodes,
            src, dst, n_edges, cnt, bucket, spill_cnt, spill);
        gather_reduce_kernel<<<(n_nodes + 15) / 16, 256, 0, stream>>>(
            h, cnt, bucket, out, n_nodes);
        spill_apply_kernel<<<1, 256, 0, stream>>>(h, spill_cnt, spill, out);
    } else {
        prep_kernel<<<8, 256, 0, stream>>>(W, Wb, nullptr, 0, nullptr);
        gemm_mfma_kernel<<<n_tiles, 256, 0, stream>>>(
            x, Wb, bias, mask_u, h, n_nodes,
            nullptr, nullptr, 0, nullptr, nullptr, nullptr, nullptr);
        zero_kernel<<<(out_size + 255) / 256, 256, 0, stream>>>((int*)d_out, out_size);
        scatter_atomic_kernel<<<(n_edges + 15) / 16, 256, 0, stream>>>(
            h, src, dst, out, n_edges);
    }
}

// Round 10
// 80.334 us; speedup vs baseline: 1.5494x; 1.2459x over previous
//
#include <hip/hip_runtime.h>

#define D 128
#define TILE_N 32      // 2 node-strips x 2 col-halves per 256-thread block
#define HPITCH 132     // bf16 pitch for epilogue LDS tile -> conflict-free banks
#define CAP 48         // bucket capacity per node; Poisson(12), P(deg>48) ~ 1e-14
#define SPILL_MAX 8192

typedef __attribute__((ext_vector_type(8))) short  short8;
typedef __attribute__((ext_vector_type(4))) float  f32x4;

__device__ inline unsigned short f32_to_bf16(float f) {
    unsigned int u = __float_as_uint(f);
    unsigned int r = (u + 0x7FFFu + ((u >> 16) & 1u)) >> 16;   // RNE
    return (unsigned short)r;
}
__device__ inline float bf16_to_f32(unsigned short s) {
    return __uint_as_float(((unsigned int)s) << 16);
}
__device__ inline short8 pack_bf16x8(float4 a, float4 b) {
    short8 u;
    u[0] = (short)f32_to_bf16(a.x); u[1] = (short)f32_to_bf16(a.y);
    u[2] = (short)f32_to_bf16(a.z); u[3] = (short)f32_to_bf16(a.w);
    u[4] = (short)f32_to_bf16(b.x); u[5] = (short)f32_to_bf16(b.y);
    u[6] = (short)f32_to_bf16(b.z); u[7] = (short)f32_to_bf16(b.w);
    return u;
}

// ---- prep: W (f32) -> Wb (bf16); zero cnt + spill counter ------------------
__global__ __launch_bounds__(256) void prep_kernel(
    const float* __restrict__ W, unsigned short* __restrict__ Wb,
    int* __restrict__ cnt, int n_nodes, int* __restrict__ spill_cnt)
{
    const int tid = blockIdx.x * 256 + threadIdx.x;
    if (tid < (D * D) / 8) {
        float4 v0 = *(const float4*)&W[tid * 8];
        float4 v1 = *(const float4*)&W[tid * 8 + 4];
        *(short8*)&Wb[tid * 8] = pack_bf16x8(v0, v1);
    }
    if (cnt && tid < n_nodes) cnt[tid] = 0;
    if (spill_cnt && tid == 0) *spill_cnt = 0;
}

// ---- GEMM + fused edge bucket-scatter --------------------------------------
// Wave (ws,cs): 16 nodes x 64 cols -> 6252 waves total (76% occupancy cap,
// was 3128/38%). VGPR kept <=64 via launch_bounds(256,8) so 8 waves/SIMD.
__global__ __launch_bounds__(256, 8) void gemm_mfma_kernel(
    const float* __restrict__ x, const unsigned short* __restrict__ Wb,
    const float* __restrict__ bias, const float* __restrict__ mask_u,
    unsigned short* __restrict__ h, int n_nodes,
    const int* __restrict__ src, const int* __restrict__ dst, int n_edges,
    int* __restrict__ cnt, int* __restrict__ bucket,
    int* __restrict__ spill_cnt, int* __restrict__ spill)
{
    __shared__ unsigned short ht[TILE_N * HPITCH];   // 8448 B
    const int t    = threadIdx.x;
    const int lane = t & 63;
    const int w    = t >> 6;
    const int ws   = w >> 1;      // node strip 0..1
    const int cs   = w & 1;       // col half 0..1
    const int fr   = lane & 15;
    const int fg   = lane >> 4;

    const int n0 = blockIdx.x * TILE_N;

    float bs[4];
    #pragma unroll
    for (int c = 0; c < 4; ++c) bs[c] = bias[64 * cs + 16 * c + fr];

    int arow = n0 + 16 * ws + fr;
    if (arow >= n_nodes) arow = n_nodes - 1;
    const float* xrow = x + (size_t)arow * D;

    f32x4 acc[4];
    #pragma unroll
    for (int c = 0; c < 4; ++c) acc[c] = (f32x4){0.f, 0.f, 0.f, 0.f};

    #pragma unroll
    for (int s = 0; s < 4; ++s) {
        float4 a0 = *(const float4*)&xrow[s * 32 + fg * 8];
        float4 a1 = *(const float4*)&xrow[s * 32 + fg * 8 + 4];
        short8 a  = pack_bf16x8(a0, a1);
        #pragma unroll
        for (int c = 0; c < 4; ++c) {
            short8 b = *(const short8*)&Wb[(64 * cs + 16 * c + fr) * D + s * 32 + fg * 8];
            acc[c] = __builtin_amdgcn_mfma_f32_16x16x32_bf16(a, b, acc[c], 0, 0, 0);
        }
    }

    // phase 1: bias + relu -> LDS tile (wave (ws,cs) owns rows 16ws.., cols 64cs..)
    #pragma unroll
    for (int c = 0; c < 4; ++c) {
        const int col = 64 * cs + 16 * c + fr;
        #pragma unroll
        for (int r = 0; r < 4; ++r) {
            const int rl = 16 * ws + fg * 4 + r;
            float v = fmaxf(acc[c][r] + bs[c], 0.f);
            ht[rl * HPITCH + col] = f32_to_bf16(v);
        }
    }
    __syncthreads();

    // phase 2: dropout + coalesced mask loads / h stores (32 rows x 16 cgroups)
    #pragma unroll
    for (int it = 0; it < 2; ++it) {
        const int idx = it * 256 + t;
        const int row = idx >> 4;
        const int cg  = idx & 15;
        const int node = n0 + row;
        if (node < n_nodes) {
            short8 hv = *(const short8*)&ht[row * HPITCH + cg * 8];
            const size_t off = (size_t)node * D + cg * 8;
            float4 m0 = *(const float4*)&mask_u[off];
            float4 m1 = *(const float4*)&mask_u[off + 4];
            short8 o;
            #pragma unroll
            for (int j = 0; j < 8; ++j) {
                float mk = (j < 4) ? ((const float*)&m0)[j] : ((const float*)&m1)[j - 4];
                float v  = bf16_to_f32((unsigned short)hv[j]) * 2.f;
                o[j] = (mk >= 0.5f) ? (short)f32_to_bf16(v) : (short)0;
            }
            *(short8*)&h[off] = o;
        }
    }

    // fused bucket-scatter tail (overlaps other blocks' tile work)
    const int stride = gridDim.x * 256;
    for (int i = blockIdx.x * 256 + t; i < n_edges; i += stride) {
        int dd  = dst[i];
        int ss  = src[i];
        int pos = atomicAdd(&cnt[dd], 1);
        if (pos < CAP) {
            bucket[dd * CAP + pos] = ss;
        } else {
            int k = atomicAdd(spill_cnt, 1);
            if (k < SPILL_MAX) { spill[2 * k] = dd; spill[2 * k + 1] = ss; }
        }
    }
}

// ---- Gather-reduce (bf16 h): 16 lanes/node over fixed-cap buckets ----------
__global__ __launch_bounds__(256) void gather_reduce_kernel(
    const unsigned short* __restrict__ h, const int* __restrict__ cnt,
    const int* __restrict__ bucket, float* __restrict__ out, int n_nodes)
{
    const int t = threadIdx.x;
    const int node = blockIdx.x * 16 + (t >> 4);
    if (node >= n_nodes) return;
    const int cb = (t & 15) * 8;
    int deg = cnt[node];
    if (deg > CAP) deg = CAP;
    const int* b = bucket + (size_t)node * CAP;

    float acc[8];
    #pragma unroll
    for (int j = 0; j < 8; ++j) acc[j] = 0.f;

    int i = 0;
    for (; i + 3 < deg; i += 4) {
        int s0 = b[i], s1 = b[i + 1], s2 = b[i + 2], s3 = b[i + 3];
        short8 v0 = *(const short8*)&h[(size_t)s0 * D + cb];
        short8 v1 = *(const short8*)&h[(size_t)s1 * D + cb];
        short8 v2 = *(const short8*)&h[(size_t)s2 * D + cb];
        short8 v3 = *(const short8*)&h[(size_t)s3 * D + cb];
        #pragma unroll
        for (int j = 0; j < 8; ++j)
            acc[j] += (bf16_to_f32((unsigned short)v0[j]) +
                       bf16_to_f32((unsigned short)v1[j])) +
                      (bf16_to_f32((unsigned short)v2[j]) +
                       bf16_to_f32((unsigned short)v3[j]));
    }
    for (; i < deg; ++i) {
        int s0 = b[i];
        short8 v0 = *(const short8*)&h[(size_t)s0 * D + cb];
        #pragma unroll
        for (int j = 0; j < 8; ++j) acc[j] += bf16_to_f32((unsigned short)v0[j]);
    }

    f32x4 o0 = (f32x4){acc[0], acc[1], acc[2], acc[3]};
    f32x4 o1 = (f32x4){acc[4], acc[5], acc[6], acc[7]};
    __builtin_nontemporal_store(o0, (f32x4*)&out[(size_t)node * D + cb]);
    __builtin_nontemporal_store(o1, (f32x4*)&out[(size_t)node * D + cb + 4]);
}

// ---- spill fix: apply overflow edges atomically (virtually never runs) -----
__global__ __launch_bounds__(256) void spill_apply_kernel(
    const unsigned short* __restrict__ h, const int* __restrict__ spill_cnt,
    const int* __restrict__ spill, float* __restrict__ out)
{
    int n = *spill_cnt;
    if (n > SPILL_MAX) n = SPILL_MAX;
    for (int e = threadIdx.x; e < n; e += 256) {
        int dd = spill[2 * e], ss = spill[2 * e + 1];
        for (int j = 0; j < D; ++j)
            atomicAdd(&out[(size_t)dd * D + j],
                      bf16_to_f32(h[(size_t)ss * D + j]));
    }
}

// ---- zero + fallback atomic scatter ----------------------------------------
__global__ __launch_bounds__(256) void zero_kernel(int* __restrict__ p, int n)
{
    int i = blockIdx.x * 256 + threadIdx.x;
    if (i < n) p[i] = 0;
}

__global__ __launch_bounds__(256) void scatter_atomic_kernel(
    const unsigned short* __restrict__ h, const int* __restrict__ src,
    const int* __restrict__ dst, float* __restrict__ out, int n_edges)
{
    const int t = threadIdx.x;
    const int e = blockIdx.x * 16 + (t >> 4);
    if (e >= n_edges) return;
    const int cb = (t & 15) * 8;
    const int s  = src[e];
    const int dd = dst[e];
    short8 v = *(const short8*)&h[(size_t)s * D + cb];
    float* o = &out[(size_t)dd * D + cb];
    #pragma unroll
    for (int j = 0; j < 8; ++j) atomicAdd(o + j, bf16_to_f32((unsigned short)v[j]));
}

extern "C" void kernel_launch(void* const* d_in, const int* in_sizes, int n_in,
                              void* d_out, int out_size, void* d_ws, size_t ws_size,
                              hipStream_t stream) {
    const float* x      = (const float*)d_in[0];
    const float* W      = (const float*)d_in[1];
    const float* bias   = (const float*)d_in[2];
    const float* mask_u = (const float*)d_in[3];
    const int*   src    = (const int*)d_in[4];
    const int*   dst    = (const int*)d_in[5];
    float* out = (float*)d_out;

    const int n_nodes = in_sizes[0] / D;
    const int n_edges = in_sizes[4];
    const int n_tiles = (n_nodes + TILE_N - 1) / TILE_N;

    // ws layout: [Wb 32KB][h bf16][cnt n][spill_cnt 1][spill 2*SPILL_MAX][bucket n*CAP]
    unsigned short* Wb = (unsigned short*)d_ws;
    const size_t wb_bytes = (size_t)D * D * sizeof(unsigned short);
    unsigned short* h  = (unsigned short*)((char*)d_ws + wb_bytes);
    const size_t h_bytes = (size_t)n_nodes * D * sizeof(unsigned short);
    int* cnt       = (int*)((char*)d_ws + wb_bytes + h_bytes);
    int* spill_cnt = cnt + n_nodes;
    int* spill     = spill_cnt + 1;
    int* bucket    = spill + 2 * SPILL_MAX;
    const size_t needed = wb_bytes + h_bytes +
        ((size_t)n_nodes + 1 + 2 * SPILL_MAX + (size_t)n_nodes * CAP) * sizeof(int);

    const int pbk = ((n_nodes > 2048 ? n_nodes : 2048) + 255) / 256;

    if (ws_size >= needed) {
        prep_kernel<<<pbk, 256, 0, stream>>>(W, Wb, cnt, n_nodes, spill_cnt);
        gemm_mfma_kernel<<<n_tiles, 256, 0, stream>>>(
            x, Wb, bias, mask_u, h, n_nodes,
            src, dst, n_edges, cnt, bucket, spill_cnt, spill);
        gather_reduce_kernel<<<(n_nodes + 15) / 16, 256, 0, stream>>>(
            h, cnt, bucket, out, n_nodes);
        spill_apply_kernel<<<1, 256, 0, stream>>>(h, spill_cnt, spill, out);
    } else {
        prep_kernel<<<8, 256, 0, stream>>>(W, Wb, nullptr, 0, nullptr);
        gemm_mfma_kernel<<<n_tiles, 256, 0, stream>>>(
            x, Wb, bias, mask_u, h, n_nodes,
            nullptr, nullptr, 0, nullptr, nullptr, nullptr, nullptr);
        zero_kernel<<<(out_size + 255) / 256, 256, 0, stream>>>((int*)d_out, out_size);
        scatter_atomic_kernel<<<(n_edges + 15) / 16, 256, 0, stream>>>(
            h, src, dst, out, n_edges);
    }
}

// Round 11
// 79.640 us; speedup vs baseline: 1.5629x; 1.0087x over previous
//
#include <hip/hip_runtime.h>

#define D 128
#define TILE_N 32      // 2 node-strips x 2 col-halves per 256-thread block
#define HPITCH 132     // bf16 pitch for epilogue LDS tile -> conflict-free banks
#define CAP 48         // bucket capacity per node; Poisson(12), P(deg>48) ~ 1e-14
#define SPILL_MAX 8192

typedef __attribute__((ext_vector_type(8))) short  short8;
typedef __attribute__((ext_vector_type(4))) float  f32x4;

__device__ inline unsigned short f32_to_bf16(float f) {
    unsigned int u = __float_as_uint(f);
    unsigned int r = (u + 0x7FFFu + ((u >> 16) & 1u)) >> 16;   // RNE
    return (unsigned short)r;
}
__device__ inline float bf16_to_f32(unsigned short s) {
    return __uint_as_float(((unsigned int)s) << 16);
}
__device__ inline short8 pack_bf16x8(float4 a, float4 b) {
    short8 u;
    u[0] = (short)f32_to_bf16(a.x); u[1] = (short)f32_to_bf16(a.y);
    u[2] = (short)f32_to_bf16(a.z); u[3] = (short)f32_to_bf16(a.w);
    u[4] = (short)f32_to_bf16(b.x); u[5] = (short)f32_to_bf16(b.y);
    u[6] = (short)f32_to_bf16(b.z); u[7] = (short)f32_to_bf16(b.w);
    return u;
}

// ---- prep: W (f32) -> Wb (bf16); zero cnt + spill counter ------------------
__global__ __launch_bounds__(256) void prep_kernel(
    const float* __restrict__ W, unsigned short* __restrict__ Wb,
    int* __restrict__ cnt, int n_nodes, int* __restrict__ spill_cnt)
{
    const int tid = blockIdx.x * 256 + threadIdx.x;
    if (tid < (D * D) / 8) {
        float4 v0 = *(const float4*)&W[tid * 8];
        float4 v1 = *(const float4*)&W[tid * 8 + 4];
        *(short8*)&Wb[tid * 8] = pack_bf16x8(v0, v1);
    }
    if (cnt && tid < n_nodes) cnt[tid] = 0;
    if (spill_cnt && tid == 0) *spill_cnt = 0;
}

// ---- GEMM + fused edge bucket-scatter, software-pipelined ------------------
// All independent loads (x frags, epilogue mask, this thread's edge pair)
// issue at kernel top -> ~14 VMEM in flight during MFMA instead of 2-8.
__global__ __launch_bounds__(256, 8) void gemm_mfma_kernel(
    const float* __restrict__ x, const unsigned short* __restrict__ Wb,
    const float* __restrict__ bias, const float* __restrict__ mask_u,
    unsigned short* __restrict__ h, int n_nodes,
    const int* __restrict__ src, const int* __restrict__ dst, int n_edges,
    int* __restrict__ cnt, int* __restrict__ bucket,
    int* __restrict__ spill_cnt, int* __restrict__ spill)
{
    __shared__ unsigned short ht[TILE_N * HPITCH];   // 8448 B
    const int t    = threadIdx.x;
    const int lane = t & 63;
    const int w    = t >> 6;
    const int ws   = w >> 1;      // node strip 0..1
    const int cs   = w & 1;       // col half 0..1
    const int fr   = lane & 15;
    const int fg   = lane >> 4;

    const int n0 = blockIdx.x * TILE_N;

    // ---- issue-early: edge pair for the fused tail -------------------------
    const int e0 = blockIdx.x * 256 + t;
    int e_dst = 0, e_src = 0;
    const bool has_e0 = (e0 < n_edges);
    if (has_e0) { e_dst = dst[e0]; e_src = src[e0]; }

    // ---- issue-early: x fragments ------------------------------------------
    int arow = n0 + 16 * ws + fr;
    if (arow >= n_nodes) arow = n_nodes - 1;
    const float* xrow = x + (size_t)arow * D;
    float4 xa[4][2];
    #pragma unroll
    for (int s = 0; s < 4; ++s) {
        xa[s][0] = *(const float4*)&xrow[s * 32 + fg * 8];
        xa[s][1] = *(const float4*)&xrow[s * 32 + fg * 8 + 4];
    }

    // ---- issue-early: epilogue mask (thread handles idx = it*256+t) --------
    float4 mk[2][2];
    int en_node[2];
    #pragma unroll
    for (int it = 0; it < 2; ++it) {
        const int idx = it * 256 + t;
        const int row = idx >> 4;
        const int cg  = idx & 15;
        int node = n0 + row;
        en_node[it] = node;
        if (node >= n_nodes) node = n_nodes - 1;   // clamped safe load
        const size_t off = (size_t)node * D + cg * 8;
        mk[it][0] = *(const float4*)&mask_u[off];
        mk[it][1] = *(const float4*)&mask_u[off + 4];
    }

    float bs[4];
    #pragma unroll
    for (int c = 0; c < 4; ++c) bs[c] = bias[64 * cs + 16 * c + fr];

    f32x4 acc[4];
    #pragma unroll
    for (int c = 0; c < 4; ++c) acc[c] = (f32x4){0.f, 0.f, 0.f, 0.f};

    #pragma unroll
    for (int s = 0; s < 4; ++s) {
        short8 a = pack_bf16x8(xa[s][0], xa[s][1]);
        #pragma unroll
        for (int c = 0; c < 4; ++c) {
            short8 b = *(const short8*)&Wb[(64 * cs + 16 * c + fr) * D + s * 32 + fg * 8];
            acc[c] = __builtin_amdgcn_mfma_f32_16x16x32_bf16(a, b, acc[c], 0, 0, 0);
        }
    }

    // phase 1: bias + relu -> LDS tile
    #pragma unroll
    for (int c = 0; c < 4; ++c) {
        const int col = 64 * cs + 16 * c + fr;
        #pragma unroll
        for (int r = 0; r < 4; ++r) {
            const int rl = 16 * ws + fg * 4 + r;
            float v = fmaxf(acc[c][r] + bs[c], 0.f);
            ht[rl * HPITCH + col] = f32_to_bf16(v);
        }
    }
    __syncthreads();

    // fused bucket-scatter (edge data preloaded; atomics drain under epilogue)
    if (has_e0) {
        int pos = atomicAdd(&cnt[e_dst], 1);
        if (pos < CAP) {
            bucket[e_dst * CAP + pos] = e_src;
        } else {
            int k = atomicAdd(spill_cnt, 1);
            if (k < SPILL_MAX) { spill[2 * k] = e_dst; spill[2 * k + 1] = e_src; }
        }
    }
    const int stride = gridDim.x * 256;
    for (int i = e0 + stride; i < n_edges; i += stride) {
        int dd  = dst[i];
        int ss  = src[i];
        int pos = atomicAdd(&cnt[dd], 1);
        if (pos < CAP) {
            bucket[dd * CAP + pos] = ss;
        } else {
            int k = atomicAdd(spill_cnt, 1);
            if (k < SPILL_MAX) { spill[2 * k] = dd; spill[2 * k + 1] = ss; }
        }
    }

    // phase 2: dropout with preloaded mask + coalesced h stores
    #pragma unroll
    for (int it = 0; it < 2; ++it) {
        const int idx = it * 256 + t;
        const int row = idx >> 4;
        const int cg  = idx & 15;
        if (en_node[it] < n_nodes) {
            short8 hv = *(const short8*)&ht[row * HPITCH + cg * 8];
            const size_t off = (size_t)en_node[it] * D + cg * 8;
            short8 o;
            #pragma unroll
            for (int j = 0; j < 8; ++j) {
                float m = (j < 4) ? ((const float*)&mk[it][0])[j]
                                  : ((const float*)&mk[it][1])[j - 4];
                float v = bf16_to_f32((unsigned short)hv[j]) * 2.f;
                o[j] = (m >= 0.5f) ? (short)f32_to_bf16(v) : (short)0;
            }
            *(short8*)&h[off] = o;
        }
    }
}

// ---- Gather-reduce (bf16 h): 16 lanes/node over fixed-cap buckets ----------
__global__ __launch_bounds__(256) void gather_reduce_kernel(
    const unsigned short* __restrict__ h, const int* __restrict__ cnt,
    const int* __restrict__ bucket, float* __restrict__ out, int n_nodes)
{
    const int t = threadIdx.x;
    const int node = blockIdx.x * 16 + (t >> 4);
    if (node >= n_nodes) return;
    const int cb = (t & 15) * 8;
    int deg = cnt[node];
    if (deg > CAP) deg = CAP;
    const int* b = bucket + (size_t)node * CAP;

    float acc[8];
    #pragma unroll
    for (int j = 0; j < 8; ++j) acc[j] = 0.f;

    int i = 0;
    for (; i + 3 < deg; i += 4) {
        int s0 = b[i], s1 = b[i + 1], s2 = b[i + 2], s3 = b[i + 3];
        short8 v0 = *(const short8*)&h[(size_t)s0 * D + cb];
        short8 v1 = *(const short8*)&h[(size_t)s1 * D + cb];
        short8 v2 = *(const short8*)&h[(size_t)s2 * D + cb];
        short8 v3 = *(const short8*)&h[(size_t)s3 * D + cb];
        #pragma unroll
        for (int j = 0; j < 8; ++j)
            acc[j] += (bf16_to_f32((unsigned short)v0[j]) +
                       bf16_to_f32((unsigned short)v1[j])) +
                      (bf16_to_f32((unsigned short)v2[j]) +
                       bf16_to_f32((unsigned short)v3[j]));
    }
    for (; i < deg; ++i) {
        int s0 = b[i];
        short8 v0 = *(const short8*)&h[(size_t)s0 * D + cb];
        #pragma unroll
        for (int j = 0; j < 8; ++j) acc[j] += bf16_to_f32((unsigned short)v0[j]);
    }

    f32x4 o0 = (f32x4){acc[0], acc[1], acc[2], acc[3]};
    f32x4 o1 = (f32x4){acc[4], acc[5], acc[6], acc[7]};
    __builtin_nontemporal_store(o0, (f32x4*)&out[(size_t)node * D + cb]);
    __builtin_nontemporal_store(o1, (f32x4*)&out[(size_t)node * D + cb + 4]);
}

// ---- spill fix: apply overflow edges atomically (virtually never runs) -----
__global__ __launch_bounds__(256) void spill_apply_kernel(
    const unsigned short* __restrict__ h, const int* __restrict__ spill_cnt,
    const int* __restrict__ spill, float* __restrict__ out)
{
    int n = *spill_cnt;
    if (n > SPILL_MAX) n = SPILL_MAX;
    for (int e = threadIdx.x; e < n; e += 256) {
        int dd = spill[2 * e], ss = spill[2 * e + 1];
        for (int j = 0; j < D; ++j)
            atomicAdd(&out[(size_t)dd * D + j],
                      bf16_to_f32(h[(size_t)ss * D + j]));
    }
}

// ---- zero + fallback atomic scatter ----------------------------------------
__global__ __launch_bounds__(256) void zero_kernel(int* __restrict__ p, int n)
{
    int i = blockIdx.x * 256 + threadIdx.x;
    if (i < n) p[i] = 0;
}

__global__ __launch_bounds__(256) void scatter_atomic_kernel(
    const unsigned short* __restrict__ h, const int* __restrict__ src,
    const int* __restrict__ dst, float* __restrict__ out, int n_edges)
{
    const int t = threadIdx.x;
    const int e = blockIdx.x * 16 + (t >> 4);
    if (e >= n_edges) return;
    const int cb = (t & 15) * 8;
    const int s  = src[e];
    const int dd = dst[e];
    short8 v = *(const short8*)&h[(size_t)s * D + cb];
    float* o = &out[(size_t)dd * D + cb];
    #pragma unroll
    for (int j = 0; j < 8; ++j) atomicAdd(o + j, bf16_to_f32((unsigned short)v[j]));
}

extern "C" void kernel_launch(void* const* d_in, const int* in_sizes, int n_in,
                              void* d_out, int out_size, void* d_ws, size_t ws_size,
                              hipStream_t stream) {
    const float* x      = (const float*)d_in[0];
    const float* W      = (const float*)d_in[1];
    const float* bias   = (const float*)d_in[2];
    const float* mask_u = (const float*)d_in[3];
    const int*   src    = (const int*)d_in[4];
    const int*   dst    = (const int*)d_in[5];
    float* out = (float*)d_out;

    const int n_nodes = in_sizes[0] / D;
    const int n_edges = in_sizes[4];
    const int n_tiles = (n_nodes + TILE_N - 1) / TILE_N;

    // ws layout: [Wb 32KB][h bf16][cnt n][spill_cnt 1][spill 2*SPILL_MAX][bucket n*CAP]
    unsigned short* Wb = (unsigned short*)d_ws;
    const size_t wb_bytes = (size_t)D * D * sizeof(unsigned short);
    unsigned short* h  = (unsigned short*)((char*)d_ws + wb_bytes);
    const size_t h_bytes = (size_t)n_nodes * D * sizeof(unsigned short);
    int* cnt       = (int*)((char*)d_ws + wb_bytes + h_bytes);
    int* spill_cnt = cnt + n_nodes;
    int* spill     = spill_cnt + 1;
    int* bucket    = spill + 2 * SPILL_MAX;
    const size_t needed = wb_bytes + h_bytes +
        ((size_t)n_nodes + 1 + 2 * SPILL_MAX + (size_t)n_nodes * CAP) * sizeof(int);

    const int pbk = ((n_nodes > 2048 ? n_nodes : 2048) + 255) / 256;

    if (ws_size >= needed) {
        prep_kernel<<<pbk, 256, 0, stream>>>(W, Wb, cnt, n_nodes, spill_cnt);
        gemm_mfma_kernel<<<n_tiles, 256, 0, stream>>>(
            x, Wb, bias, mask_u, h, n_nodes,
            src, dst, n_edges, cnt, bucket, spill_cnt, spill);
        gather_reduce_kernel<<<(n_nodes + 15) / 16, 256, 0, stream>>>(
            h, cnt, bucket, out, n_nodes);
        spill_apply_kernel<<<1, 256, 0, stream>>>(h, spill_cnt, spill, out);
    } else {
        prep_kernel<<<8, 256, 0, stream>>>(W, Wb, nullptr, 0, nullptr);
        gemm_mfma_kernel<<<n_tiles, 256, 0, stream>>>(
            x, Wb, bias, mask_u, h, n_nodes,
            nullptr, nullptr, 0, nullptr, nullptr, nullptr, nullptr);
        zero_kernel<<<(out_size + 255) / 256, 256, 0, stream>>>((int*)d_out, out_size);
        scatter_atomic_kernel<<<(n_edges + 15) / 16, 256, 0, stream>>>(
            h, src, dst, out, n_edges);
    }
}